// Round 4
// baseline (1647.186 us; speedup 1.0000x reference)
//
#include <hip/hip_runtime.h>
#include <hip/hip_bf16.h>
#include <stdint.h>

#define K_DIM 4096
#define N_DIM 11008
#define BM 256
#define BN 128
#define NT (K_DIM / 64)   // 64 K-tiles of BK=64

typedef _Float16 half8 __attribute__((ext_vector_type(8)));
typedef float floatx4 __attribute__((ext_vector_type(4)));

// Dequant one packed int32 (8 int4 along k) -> fp16x8 B-fragment in k-order.
// nibble j at bits [4j+3:4j]; w = (q-8)*s. s is fp16-exact (promoted to fp32
// by the harness), (q-8) is a 4-bit int -> product exact in fp32; one 2^-12
// rounding on the fp16 convert.
__device__ __forceinline__ half8 dequant_word_f16(uint32_t w, float s) {
    half8 r;
    #pragma unroll
    for (int j = 0; j < 8; ++j) {
        int q = (int)((w >> (4 * j)) & 0xFu);
        r[j] = (_Float16)((float)(q - 8) * s);
    }
    return r;
}

// LDS-free correctness anchor: fp32 inputs (harness promotes fp16->fp32),
// fp16 MFMA, fp32 output. A fragment = 8 consecutive fp32 of one X row,
// loaded directly from global and converted (exact: values are fp16-exact).
__global__ __launch_bounds__(256, 2)
void qgemm_kernel(const float* __restrict__ X,
                  const int* __restrict__ Wp,
                  const float* __restrict__ Sc,
                  const float* __restrict__ Bias,
                  float* __restrict__ Out)
{
    const int tid = threadIdx.x;
    const int m0 = blockIdx.x * BM;          // 16 m-blocks
    const int n0 = blockIdx.y * BN;          // 86 n-blocks

    const int lane = tid & 63;
    const int wid  = tid >> 6;
    const int wm   = wid >> 1;               // 0..1 (m half: 128 rows)
    const int wn   = wid & 1;                // 0..1 (n half: 64 cols)
    const int q    = lane >> 4;              // quad 0..3
    const int tt   = lane & 15;

    // B fragment: lane's word = packed[kt*8 + ks*4 + q][ncol + j*16]
    const int ncol = n0 + wn * 64 + tt;
    const int* bPtr = Wp + (size_t)q * N_DIM + ncol;
    const float* scPtr = Sc + ncol;

    // A fragment: lane reads X[m0 + wm*128 + i*16 + tt][k..k+7], k = kt*64+ks*32+q*8
    const float* aBase = X + (size_t)(m0 + wm * 128 + tt) * K_DIM + q * 8;

    floatx4 acc[8][4];
    #pragma unroll
    for (int i = 0; i < 8; ++i)
        #pragma unroll
        for (int j = 0; j < 4; ++j)
            acc[i][j] = floatx4{0.f, 0.f, 0.f, 0.f};

    float s[4];

    for (int kt = 0; kt < NT; ++kt) {
        // per-128-group scales (group = kt>>1), reload at even kt (fp32 loads)
        if ((kt & 1) == 0) {
            const float* sp = scPtr + (size_t)(kt >> 1) * N_DIM;
            #pragma unroll
            for (int j = 0; j < 4; ++j) s[j] = sp[j * 16];
        }

        // load + dequant this tile's B words (8 per lane)
        const int* bp = bPtr + (size_t)kt * 8 * N_DIM;
        uint32_t wv[8];
        #pragma unroll
        for (int ks = 0; ks < 2; ++ks)
            #pragma unroll
            for (int j = 0; j < 4; ++j)
                wv[ks * 4 + j] = (uint32_t)bp[(size_t)(ks * 4) * N_DIM + j * 16];

        half8 bf[8];
        #pragma unroll
        for (int ks = 0; ks < 2; ++ks)
            #pragma unroll
            for (int j = 0; j < 4; ++j)
                bf[ks * 4 + j] = dequant_word_f16(wv[ks * 4 + j], s[j]);

        // compute: 2 k-steps x 8 m-tiles x 4 n-tiles
        #pragma unroll
        for (int ks = 0; ks < 2; ++ks) {
            const size_t ko = (size_t)(kt * 64 + ks * 32);
            #pragma unroll
            for (int i = 0; i < 8; ++i) {
                const float* ap = aBase + (size_t)i * 16 * K_DIM + ko;
                float4 lo = *(const float4*)ap;
                float4 hi = *(const float4*)(ap + 4);
                half8 af;
                af[0] = (_Float16)lo.x; af[1] = (_Float16)lo.y;
                af[2] = (_Float16)lo.z; af[3] = (_Float16)lo.w;
                af[4] = (_Float16)hi.x; af[5] = (_Float16)hi.y;
                af[6] = (_Float16)hi.z; af[7] = (_Float16)hi.w;
                #pragma unroll
                for (int j = 0; j < 4; ++j)
                    acc[i][j] = __builtin_amdgcn_mfma_f32_16x16x32_f16(
                        af, bf[ks * 4 + j], acc[i][j], 0, 0, 0);
            }
        }
    }

    // epilogue: C/D layout col=lane&15, row=(lane>>4)*4+r; fp32 output + bias
    #pragma unroll
    for (int j = 0; j < 4; ++j) {
        const int n = ncol + j * 16;
        const float bv = Bias[n];
        #pragma unroll
        for (int i = 0; i < 8; ++i) {
            const int mrow = m0 + wm * 128 + i * 16 + q * 4;
            #pragma unroll
            for (int r = 0; r < 4; ++r)
                Out[(size_t)(mrow + r) * N_DIM + n] = acc[i][j][r] + bv;
        }
    }
}

extern "C" void kernel_launch(void* const* d_in, const int* in_sizes, int n_in,
                              void* d_out, int out_size, void* d_ws, size_t ws_size,
                              hipStream_t stream) {
    (void)in_sizes; (void)n_in; (void)out_size; (void)d_ws; (void)ws_size;
    const float* X    = (const float*)d_in[0];
    const int*   Wp   = (const int*)d_in[1];
    const float* Sc   = (const float*)d_in[2];
    const float* Bias = (const float*)d_in[3];
    float*       Out  = (float*)d_out;

    dim3 grid(4096 / BM, N_DIM / BN);   // (16, 86)
    qgemm_kernel<<<grid, 256, 0, stream>>>(X, Wp, Sc, Bias, Out);
}

// Round 5
// 695.146 us; speedup vs baseline: 2.3696x; 2.3696x over previous
//
#include <hip/hip_runtime.h>
#include <hip/hip_bf16.h>
#include <stdint.h>

#define K_DIM 4096
#define N_DIM 11008
#define BM 256
#define BN 128
#define NT (K_DIM / 64)   // 64 K-tiles of BK=64

typedef _Float16 half8 __attribute__((ext_vector_type(8)));
typedef float floatx4 __attribute__((ext_vector_type(4)));

typedef const uint32_t __attribute__((address_space(1)))* gas_u32p;
typedef uint32_t __attribute__((address_space(3)))* las_u32p;

// async global->LDS, 16B per lane; LDS dest = wave-uniform base + lane*16.
__device__ __forceinline__ void glds16(const void* g, void* l) {
    __builtin_amdgcn_global_load_lds((gas_u32p)g, (las_u32p)l, 16, 0, 0);
}

// Dequant one packed int32 (8 int4 along k) -> fp16x8 B-fragment, k-order.
// w = (q-8)*s; s is fp16-exact (harness promoted fp16->fp32), product exact
// in fp32, single 2^-12 rounding at the fp16 convert. (R4-validated: 0.125)
__device__ __forceinline__ half8 dequant_word_f16(uint32_t w, float s) {
    half8 r;
    #pragma unroll
    for (int j = 0; j < 8; ++j) {
        int q = (int)((w >> (4 * j)) & 0xFu);
        r[j] = (_Float16)((float)(q - 8) * s);
    }
    return r;
}

// ---------------- pre-pass: X fp32 -> fp16 (exact) ----------------
__global__ __launch_bounds__(256)
void cvt_kernel(const float* __restrict__ X, _Float16* __restrict__ Xh) {
    size_t idx = (size_t)blockIdx.x * 256 + threadIdx.x;   // 8 elts/thread
    size_t base = idx * 8;
    float4 a = *(const float4*)(X + base);
    float4 b = *(const float4*)(X + base + 4);
    half8 h;
    h[0] = (_Float16)a.x; h[1] = (_Float16)a.y;
    h[2] = (_Float16)a.z; h[3] = (_Float16)a.w;
    h[4] = (_Float16)b.x; h[5] = (_Float16)b.y;
    h[6] = (_Float16)b.z; h[7] = (_Float16)b.w;
    *(half8*)(Xh + base) = h;
}

// ---------------- main: LDS-staged A (fp16), register-dequant B ----------------
__global__ __launch_bounds__(256, 2)
void qgemm_lds(const _Float16* __restrict__ Xh,
               const int* __restrict__ Wp,
               const float* __restrict__ Sc,
               const float* __restrict__ Bias,
               float* __restrict__ Out)
{
    // A tile 256x64 fp16 = 32 KB, stored as XOR-swizzled 16B chunks:
    // chunk (row, c) lands at slot row*8 + (c ^ (row&7)).
    __shared__ half8 As[BM * 8];   // 2048 chunks * 16B

    const int tid = threadIdx.x;
    const int m0 = blockIdx.x * BM;          // 16 m-blocks (x mod 8 -> XCD affinity)
    const int n0 = blockIdx.y * BN;          // 86 n-blocks

    const int lane = tid & 63;
    const int wid  = tid >> 6;
    const int wm   = wid >> 1;               // m half (128 rows)
    const int wn   = wid & 1;                // n half (64 cols)
    const int q    = lane >> 4;              // quad 0..3
    const int tt   = lane & 15;

    // staging: thread t, iter i stages global chunk c of row i*32 + (t>>3)
    // into LDS slot i*256 + t;  c = (t&7) ^ ((t>>3)&7)  (constant over i).
    const int arow = tid >> 3;
    const int ac   = (tid & 7) ^ (arow & 7);
    const _Float16* aSrc = Xh + (size_t)(m0 + arow) * K_DIM + ac * 8;

    // B fragment: lane's word = packed[kt*8 + ks*4 + q][ncol + j*16]
    const int ncol = n0 + wn * 64 + tt;
    const int* bPtr = Wp + (size_t)q * N_DIM + ncol;
    const float* scPtr = Sc + ncol;

    floatx4 acc[8][4];
    #pragma unroll
    for (int i = 0; i < 8; ++i)
        #pragma unroll
        for (int j = 0; j < 4; ++j)
            acc[i][j] = floatx4{0.f, 0.f, 0.f, 0.f};

    // fragment read bases (bytes): row = wm*128 + i*16 + tt, chunk = ks*4+q,
    // swizzled slot = (ks*4+q) ^ (tt&7)  (row&7 == tt&7 here).
    const int x7  = tt & 7;
    const int rb0 = tt * 128 + ((0 * 4 + q) ^ x7) * 16;
    const int rb1 = tt * 128 + ((1 * 4 + q) ^ x7) * 16;
    const char* asBase = (const char*)As + wm * 16384;

    // prologue: group-0 scales + tile-0 words
    float s[4], sn[4];
    #pragma unroll
    for (int j = 0; j < 4; ++j) s[j] = scPtr[j * 16];
    uint32_t wv[8];
    #pragma unroll
    for (int ks = 0; ks < 2; ++ks)
        #pragma unroll
        for (int j = 0; j < 4; ++j)
            wv[ks * 4 + j] = (uint32_t)bPtr[(size_t)(ks * 4) * N_DIM + j * 16];

    for (int kt = 0; kt < NT; ++kt) {
        // commit prefetched scales at group boundary (uniform branch)
        if (kt > 0 && (kt & 1) == 0) {
            #pragma unroll
            for (int j = 0; j < 4; ++j) s[j] = sn[j];
        }

        // issue A DMA for this tile (8 x 16B per thread = 32 KB)
        #pragma unroll
        for (int i = 0; i < 8; ++i)
            glds16(aSrc + (size_t)i * 32 * K_DIM + kt * 64,
                   (char*)As + (size_t)(i * 256 + tid) * 16);

        // dequant current words (registers only)
        half8 bf[8];
        #pragma unroll
        for (int ks = 0; ks < 2; ++ks)
            #pragma unroll
            for (int j = 0; j < 4; ++j)
                bf[ks * 4 + j] = dequant_word_f16(wv[ks * 4 + j], s[j]);

        // prefetch next tile's words (+ next group's scales); their drain
        // rides the barrier's vmcnt(0) that the A DMA requires anyway
        if (kt + 1 < NT) {
            const int* bp = bPtr + (size_t)(kt + 1) * 8 * N_DIM;
            #pragma unroll
            for (int ks = 0; ks < 2; ++ks)
                #pragma unroll
                for (int j = 0; j < 4; ++j)
                    wv[ks * 4 + j] = (uint32_t)bp[(size_t)(ks * 4) * N_DIM + j * 16];
            if (kt & 1) {
                const float* sp = scPtr + (size_t)((kt + 1) >> 1) * N_DIM;
                #pragma unroll
                for (int j = 0; j < 4; ++j) sn[j] = sp[j * 16];
            }
        }

        __syncthreads();   // drains vmcnt(0): A DMA (+ B prefetch) complete

        // compute: 2 k-steps x 8 m-tiles x 4 n-tiles = 64 MFMA
        #pragma unroll
        for (int ks = 0; ks < 2; ++ks) {
            const int rb = ks ? rb1 : rb0;
            #pragma unroll
            for (int i = 0; i < 8; ++i) {
                half8 af = *(const half8*)(asBase + rb + i * 2048);
                #pragma unroll
                for (int j = 0; j < 4; ++j)
                    acc[i][j] = __builtin_amdgcn_mfma_f32_16x16x32_f16(
                        af, bf[ks * 4 + j], acc[i][j], 0, 0, 0);
            }
        }

        __syncthreads();   // all reads done before next tile's DMA overwrites
    }

    // epilogue: C/D layout col=lane&15, row=(lane>>4)*4+r; fp32 out + bias
    #pragma unroll
    for (int j = 0; j < 4; ++j) {
        const int n = ncol + j * 16;
        const float bv = Bias[n];
        #pragma unroll
        for (int i = 0; i < 8; ++i) {
            const int mrow = m0 + wm * 128 + i * 16 + q * 4;
            #pragma unroll
            for (int r = 0; r < 4; ++r)
                Out[(size_t)(mrow + r) * N_DIM + n] = acc[i][j][r] + bv;
        }
    }
}

// ---------------- fallback (R4, validated): direct-from-global A ----------------
__global__ __launch_bounds__(256, 2)
void qgemm_direct(const float* __restrict__ X,
                  const int* __restrict__ Wp,
                  const float* __restrict__ Sc,
                  const float* __restrict__ Bias,
                  float* __restrict__ Out)
{
    const int tid = threadIdx.x;
    const int m0 = blockIdx.x * BM;
    const int n0 = blockIdx.y * BN;
    const int lane = tid & 63;
    const int wid  = tid >> 6;
    const int wm   = wid >> 1;
    const int wn   = wid & 1;
    const int q    = lane >> 4;
    const int tt   = lane & 15;

    const int ncol = n0 + wn * 64 + tt;
    const int* bPtr = Wp + (size_t)q * N_DIM + ncol;
    const float* scPtr = Sc + ncol;
    const float* aBase = X + (size_t)(m0 + wm * 128 + tt) * K_DIM + q * 8;

    floatx4 acc[8][4];
    #pragma unroll
    for (int i = 0; i < 8; ++i)
        #pragma unroll
        for (int j = 0; j < 4; ++j)
            acc[i][j] = floatx4{0.f, 0.f, 0.f, 0.f};

    float s[4];
    for (int kt = 0; kt < NT; ++kt) {
        if ((kt & 1) == 0) {
            const float* sp = scPtr + (size_t)(kt >> 1) * N_DIM;
            #pragma unroll
            for (int j = 0; j < 4; ++j) s[j] = sp[j * 16];
        }
        const int* bp = bPtr + (size_t)kt * 8 * N_DIM;
        uint32_t wv[8];
        #pragma unroll
        for (int ks = 0; ks < 2; ++ks)
            #pragma unroll
            for (int j = 0; j < 4; ++j)
                wv[ks * 4 + j] = (uint32_t)bp[(size_t)(ks * 4) * N_DIM + j * 16];
        half8 bf[8];
        #pragma unroll
        for (int ks = 0; ks < 2; ++ks)
            #pragma unroll
            for (int j = 0; j < 4; ++j)
                bf[ks * 4 + j] = dequant_word_f16(wv[ks * 4 + j], s[j]);
        #pragma unroll
        for (int ks = 0; ks < 2; ++ks) {
            const size_t ko = (size_t)(kt * 64 + ks * 32);
            #pragma unroll
            for (int i = 0; i < 8; ++i) {
                const float* ap = aBase + (size_t)i * 16 * K_DIM + ko;
                float4 lo = *(const float4*)ap;
                float4 hi = *(const float4*)(ap + 4);
                half8 af;
                af[0] = (_Float16)lo.x; af[1] = (_Float16)lo.y;
                af[2] = (_Float16)lo.z; af[3] = (_Float16)lo.w;
                af[4] = (_Float16)hi.x; af[5] = (_Float16)hi.y;
                af[6] = (_Float16)hi.z; af[7] = (_Float16)hi.w;
                #pragma unroll
                for (int j = 0; j < 4; ++j)
                    acc[i][j] = __builtin_amdgcn_mfma_f32_16x16x32_f16(
                        af, bf[ks * 4 + j], acc[i][j], 0, 0, 0);
            }
        }
    }
    #pragma unroll
    for (int j = 0; j < 4; ++j) {
        const int n = ncol + j * 16;
        const float bv = Bias[n];
        #pragma unroll
        for (int i = 0; i < 8; ++i) {
            const int mrow = m0 + wm * 128 + i * 16 + q * 4;
            #pragma unroll
            for (int r = 0; r < 4; ++r)
                Out[(size_t)(mrow + r) * N_DIM + n] = acc[i][j][r] + bv;
        }
    }
}

extern "C" void kernel_launch(void* const* d_in, const int* in_sizes, int n_in,
                              void* d_out, int out_size, void* d_ws, size_t ws_size,
                              hipStream_t stream) {
    (void)in_sizes; (void)n_in; (void)out_size;
    const float* X    = (const float*)d_in[0];
    const int*   Wp   = (const int*)d_in[1];
    const float* Sc   = (const float*)d_in[2];
    const float* Bias = (const float*)d_in[3];
    float*       Out  = (float*)d_out;

    dim3 grid(4096 / BM, N_DIM / BN);   // (16, 86)
    const size_t needed = (size_t)4096 * K_DIM * sizeof(_Float16);  // 33.5 MB

    if (ws_size >= needed) {
        _Float16* Xh = (_Float16*)d_ws;
        cvt_kernel<<<(4096 * K_DIM) / (256 * 8), 256, 0, stream>>>(X, Xh);
        qgemm_lds<<<grid, 256, 0, stream>>>(Xh, Wp, Sc, Bias, Out);
    } else {
        qgemm_direct<<<grid, 256, 0, stream>>>(X, Wp, Sc, Bias, Out);
    }
}